// Round 11
// baseline (166.025 us; speedup 1.0000x reference)
//
#include <hip/hip_runtime.h>
#include <math.h>

#define N_NODES  32
#define N_HEADS  4
#define HEAD_DIM 64
#define CDIM     256           // N_HEADS * HEAD_DIM == channels
#define HWPIX    9216          // 96*96
#define ROWF4    2304          // HWPIX/4 float4 per (n,c) row
#define E_BASE   512
#define E_TOT    544           // + 32 self loops
#define NEG_SLOPE 0.2f
#define XS       257           // LDS stride for x tile (conflict-free)

// ---------------------------------------------------------------------------
// Kernel 1: spatial mean pool — R7 structure, byte-identical (44.9 us, at BW
// roofline per R8 subtraction probe).
// ---------------------------------------------------------------------------
__global__ __launch_bounds__(256, 4) void pool_kernel(const float* __restrict__ roi,
                                                      float* __restrict__ x) {
    const int wave = threadIdx.x >> 6, lane = threadIdx.x & 63;
    const int row = blockIdx.x * 4 + wave;            // 0..8191  (n*256+c)
    const float4* p = reinterpret_cast<const float4*>(roi) + (size_t)row * ROWF4 + lane;

    float4 A[12], B[12];
    float s = 0.f;

#pragma unroll
    for (int j = 0; j < 12; ++j) A[j] = p[j * 64];              // chunk 0 -> A
#pragma unroll
    for (int j = 0; j < 12; ++j) B[j] = p[(12 + j) * 64];       // chunk 1 -> B
#pragma unroll
    for (int j = 0; j < 12; ++j) s += (A[j].x + A[j].y) + (A[j].z + A[j].w);
#pragma unroll
    for (int j = 0; j < 12; ++j) A[j] = p[(24 + j) * 64];       // chunk 2 -> A
#pragma unroll
    for (int j = 0; j < 12; ++j) s += (B[j].x + B[j].y) + (B[j].z + B[j].w);
#pragma unroll
    for (int j = 0; j < 12; ++j) s += (A[j].x + A[j].y) + (A[j].z + A[j].w);

#pragma unroll
    for (int off = 32; off; off >>= 1) s += __shfl_down(s, off);
    if (lane == 0) x[row] = s * (1.0f / (float)HWPIX);
}

// ---------------------------------------------------------------------------
// Kernel 2: full GAT + classifier — BYTE-IDENTICAL to R7.
// PROBE ROUND: launched 1x for real + 4x into scratch to measure
// (gat + launch gap) by subtraction vs R7's 72.5 us.
// ---------------------------------------------------------------------------
__global__ __launch_bounds__(256) void gat_kernel(const int* __restrict__ edge_index,
                                                  const float* __restrict__ x,
                                                  const float* __restrict__ W,
                                                  const float* __restrict__ a_src,
                                                  const float* __restrict__ a_dst,
                                                  const float* __restrict__ gat_bias,
                                                  const float* __restrict__ cls_W,
                                                  const float* __restrict__ cls_b,
                                                  float* __restrict__ out) {
    const int n = blockIdx.x;                         // dst node this block owns
    const int t = threadIdx.x;

    __shared__ float    xs[N_NODES * XS];             // x tile, stride 257
    __shared__ __align__(16) float asl[CDIM];         // a_src flat
    __shared__ __align__(16) float adl[CDIM];         // a_dst flat
    __shared__ float    was[CDIM * N_HEADS];          // W . a_src
    __shared__ float    wad[CDIM * N_HEADS];          // W . a_dst
    __shared__ float    als[N_NODES * N_HEADS];       // alpha_src, all nodes
    __shared__ float    adn[N_HEADS];                 // alpha_dst, own node
    __shared__ unsigned msegu[N_HEADS];
    __shared__ float    dseg[N_HEADS];
    __shared__ float    M[N_NODES * N_HEADS];         // attention row [s][hd]
    __shared__ float    y[N_HEADS * CDIM];
    __shared__ float    sv[CDIM];
    __shared__ float    red[8][32];

    // stage a-vectors; barrier BEFORE issuing the big load streams so the
    // x/W global-load latency still overlaps phase-0 compute.
    asl[t] = a_src[t];
    adl[t] = a_dst[t];
    if (t < N_HEADS) { msegu[t] = 0u; dseg[t] = 0.f; }
    if (t < N_NODES * N_HEADS) M[t] = 0.f;
    __syncthreads();

    // stage x into LDS (8 float4 / thread)
#pragma unroll
    for (int k = 0; k < 8; ++k) {
        const int i4 = t + k * 256;                   // 0..2047
        const float4 v = ((const float4*)x)[i4];
        const int i = i4 * 4, s = i >> 8, c = i & 255;
        xs[s * XS + c + 0] = v.x;
        xs[s * XS + c + 1] = v.y;
        xs[s * XS + c + 2] = v.z;
        xs[s * XS + c + 3] = v.w;
    }

    // phase 0: Wa vectors. Thread t owns channel c = t; W row t is 1 KB
    // coalesced float4 x16-unroll; a-vectors are uniform LDS broadcasts.
    {
        float accs[N_HEADS] = {0.f, 0.f, 0.f, 0.f};
        float accd[N_HEADS] = {0.f, 0.f, 0.f, 0.f};
        const float4* wr  = (const float4*)(W + t * CDIM);
        const float4* as4 = (const float4*)asl;
        const float4* ad4 = (const float4*)adl;
#pragma unroll 16
        for (int q = 0; q < 64; ++q) {                // q -> head q>>4
            const float4 w = wr[q], av = as4[q], dv = ad4[q];
            const int hd = q >> 4;
            accs[hd] += w.x * av.x + w.y * av.y + w.z * av.z + w.w * av.w;
            accd[hd] += w.x * dv.x + w.y * dv.y + w.z * dv.z + w.w * dv.w;
        }
#pragma unroll
        for (int hd = 0; hd < N_HEADS; ++hd) {
            was[t * N_HEADS + hd] = accs[hd];
            wad[t * N_HEADS + hd] = accd[hd];
        }
    }
    __syncthreads();

    // alphas: als[s,hd] = xs[s,:] . was[:,hd];  adn[hd] = xs[n,:] . wad[:,hd]
    if (t < 132) {
        if (t < 128) {
            const int s = t >> 2, hd = t & 3;
            const float* xrow = &xs[s * XS];
            float acc = 0.f;
#pragma unroll 8
            for (int c = 0; c < CDIM; ++c) acc += xrow[c] * was[c * N_HEADS + hd];
            als[t] = acc;
        } else {
            const int hd = t - 128;
            const float* xrow = &xs[n * XS];
            float acc = 0.f;
#pragma unroll 8
            for (int c = 0; c < CDIM; ++c) acc += xrow[c] * wad[c * N_HEADS + hd];
            adn[hd] = acc;
        }
    }
    __syncthreads();

    // pass A: segment max over edges into n (monotone uint atomicMax)
    for (int e = t; e < E_TOT; e += 256) {
        int s0, d;
        if (e < E_BASE) { s0 = edge_index[e]; d = edge_index[E_BASE + e]; }
        else            { s0 = e - E_BASE;    d = s0; }          // self loops
        if (d == n) {
#pragma unroll
            for (int hd = 0; hd < N_HEADS; ++hd) {
                float v = als[s0 * N_HEADS + hd] + adn[hd];
                v = (v >= 0.f) ? v : NEG_SLOPE * v;
                const int iv = __float_as_int(v);
                const unsigned key = (iv < 0) ? ~(unsigned)iv
                                              : ((unsigned)iv | 0x80000000u);
                atomicMax(&msegu[hd], key);
            }
        }
    }
    __syncthreads();

    float mx[N_HEADS];
#pragma unroll
    for (int hd = 0; hd < N_HEADS; ++hd) {
        const unsigned key = msegu[hd];
        const int im = (key & 0x80000000u) ? (int)(key & 0x7fffffffu) : (int)~key;
        mx[hd] = __int_as_float(im);
    }

    // pass B: exp, denominator, unnormalized attention row (dups sum correctly)
    for (int e = t; e < E_TOT; e += 256) {
        int s0, d;
        if (e < E_BASE) { s0 = edge_index[e]; d = edge_index[E_BASE + e]; }
        else            { s0 = e - E_BASE;    d = s0; }
        if (d == n) {
#pragma unroll
            for (int hd = 0; hd < N_HEADS; ++hd) {
                float v = als[s0 * N_HEADS + hd] + adn[hd];
                v = (v >= 0.f) ? v : NEG_SLOPE * v;
                const float ex = expf(v - mx[hd]);
                atomicAdd(&dseg[hd], ex);
                atomicAdd(&M[s0 * N_HEADS + hd], ex);
            }
        }
    }
    __syncthreads();

    if (t < N_NODES * N_HEADS) M[t] /= dseg[t & 3];
    __syncthreads();

    // y[hd,c] = sum_s M[s,hd] * xs[s,c]   (thread: hd=t>>6, c = lane + 64k)
    {
        const int hd = t >> 6, l = t & 63;
        float acc0 = 0.f, acc1 = 0.f, acc2 = 0.f, acc3 = 0.f;
#pragma unroll
        for (int s = 0; s < N_NODES; ++s) {
            const float m = M[s * N_HEADS + hd];      // wave-uniform broadcast
            const float* xrow = &xs[s * XS + l];
            acc0 += m * xrow[0];
            acc1 += m * xrow[64];
            acc2 += m * xrow[128];
            acc3 += m * xrow[192];
        }
        y[hd * CDIM + l]       = acc0;
        y[hd * CDIM + l + 64]  = acc1;
        y[hd * CDIM + l + 128] = acc2;
        y[hd * CDIM + l + 192] = acc3;
    }
    __syncthreads();

    // out_gat[t] = sum_c y[hd(t),c] * W[c,t] + bias; then SiLU
    {
        const int head = t >> 6;
        const float* yrow = &y[head * CDIM];
        float acc = 0.f;
#pragma unroll 16
        for (int c = 0; c < CDIM; ++c) acc += yrow[c] * W[c * CDIM + t];
        const float v = acc + gat_bias[t];
        sv[t] = v / (1.0f + expf(-v));                // SiLU
    }
    __syncthreads();

    // classifier: 8 partial groups x 32 cols (cls_W from L2), tree reduce
    {
        const int j = t & 31, g = t >> 5;
        float a = 0.f;
#pragma unroll
        for (int c0 = 0; c0 < 32; ++c0) {
            const int c = g * 32 + c0;
            a += sv[c] * cls_W[c * 32 + j];           // coalesced, L2-hot
        }
        red[g][j] = a;
    }
    __syncthreads();
    if (t < 32) {
        float s2 = cls_b[t];
#pragma unroll
        for (int g2 = 0; g2 < 8; ++g2) s2 += red[g2][t];
        out[n * 32 + t] = s2;
    }
}

// ---------------------------------------------------------------------------
extern "C" void kernel_launch(void* const* d_in, const int* in_sizes, int n_in,
                              void* d_out, int out_size, void* d_ws, size_t ws_size,
                              hipStream_t stream) {
    const float* roi   = (const float*)d_in[0];
    const int*   eidx  = (const int*)d_in[1];
    const float* W     = (const float*)d_in[2];
    const float* a_src = (const float*)d_in[3];
    const float* a_dst = (const float*)d_in[4];
    const float* gbias = (const float*)d_in[5];
    const float* clsW  = (const float*)d_in[6];
    const float* clsb  = (const float*)d_in[7];
    float* out = (float*)d_out;

    float* x    = (float*)d_ws;                // [8192] floats
    float* out2 = x + 8192;                    // probe scratch (inert)

    pool_kernel<<<(N_NODES * CDIM) / 4, 256, 0, stream>>>(roi, x);
    gat_kernel<<<N_NODES, 256, 0, stream>>>(eidx, x, W, a_src, a_dst,
                                            gbias, clsW, clsb, out);
    // ---- PROBE: 4 inert replicas to measure (gat + gap) by subtraction ----
    gat_kernel<<<N_NODES, 256, 0, stream>>>(eidx, x, W, a_src, a_dst,
                                            gbias, clsW, clsb, out2);
    gat_kernel<<<N_NODES, 256, 0, stream>>>(eidx, x, W, a_src, a_dst,
                                            gbias, clsW, clsb, out2);
    gat_kernel<<<N_NODES, 256, 0, stream>>>(eidx, x, W, a_src, a_dst,
                                            gbias, clsW, clsb, out2);
    gat_kernel<<<N_NODES, 256, 0, stream>>>(eidx, x, W, a_src, a_dst,
                                            gbias, clsW, clsb, out2);
}

// Round 12
// 71.321 us; speedup vs baseline: 2.3279x; 2.3279x over previous
//
#include <hip/hip_runtime.h>
#include <math.h>

#define N_NODES  32
#define N_HEADS  4
#define HEAD_DIM 64
#define CDIM     256           // N_HEADS * HEAD_DIM == channels
#define HWPIX    9216          // 96*96
#define ROWF4    2304          // HWPIX/4 float4 per (n,c) row
#define E_BASE   512
#define E_TOT    544           // + 32 self loops
#define NEG_SLOPE 0.2f
#define XS       257           // LDS stride for x tile (conflict-free)

// ---------------------------------------------------------------------------
// Kernel 1: spatial mean pool — byte-identical to R7 (44.9 us, at the
// 302 MB / 6.9 TB/s roofline per the R8 subtraction probe).
// ---------------------------------------------------------------------------
__global__ __launch_bounds__(256, 4) void pool_kernel(const float* __restrict__ roi,
                                                      float* __restrict__ x) {
    const int wave = threadIdx.x >> 6, lane = threadIdx.x & 63;
    const int row = blockIdx.x * 4 + wave;            // 0..8191  (n*256+c)
    const float4* p = reinterpret_cast<const float4*>(roi) + (size_t)row * ROWF4 + lane;

    float4 A[12], B[12];
    float s = 0.f;

#pragma unroll
    for (int j = 0; j < 12; ++j) A[j] = p[j * 64];              // chunk 0 -> A
#pragma unroll
    for (int j = 0; j < 12; ++j) B[j] = p[(12 + j) * 64];       // chunk 1 -> B
#pragma unroll
    for (int j = 0; j < 12; ++j) s += (A[j].x + A[j].y) + (A[j].z + A[j].w);
#pragma unroll
    for (int j = 0; j < 12; ++j) A[j] = p[(24 + j) * 64];       // chunk 2 -> A
#pragma unroll
    for (int j = 0; j < 12; ++j) s += (B[j].x + B[j].y) + (B[j].z + B[j].w);
#pragma unroll
    for (int j = 0; j < 12; ++j) s += (A[j].x + A[j].y) + (A[j].z + A[j].w);

#pragma unroll
    for (int off = 32; off; off >>= 1) s += __shfl_down(s, off);
    if (lane == 0) x[row] = s * (1.0f / (float)HWPIX);
}

// ---------------------------------------------------------------------------
// Kernel 2: GAT + classifier, latency-rewritten (R11 probe: was 23.4 us).
// - all independent global loads issued first (x, a, edges, bias, cls_b)
// - Wa W-read unroll 32 (2 latency batches)
// - out_gat: coalesced float4 W columns + 4-way LDS reduce (was 256 scalar)
// - classifier fully unrolled (1 flight batch)
// ---------------------------------------------------------------------------
__global__ __launch_bounds__(256) void gat_kernel(const int* __restrict__ edge_index,
                                                  const float* __restrict__ x,
                                                  const float* __restrict__ W,
                                                  const float* __restrict__ a_src,
                                                  const float* __restrict__ a_dst,
                                                  const float* __restrict__ gat_bias,
                                                  const float* __restrict__ cls_W,
                                                  const float* __restrict__ cls_b,
                                                  float* __restrict__ out) {
    const int n = blockIdx.x;                         // dst node this block owns
    const int t = threadIdx.x;
    const int wavg = t >> 6, lane = t & 63;

    __shared__ float    xs[N_NODES * XS];             // 32,896 B
    __shared__ __align__(16) float asl[CDIM];         // a_src flat
    __shared__ __align__(16) float adl[CDIM];         // a_dst flat
    __shared__ float    was[CDIM * N_HEADS];          // W . a_src  [c][hd]
    __shared__ float    wad[CDIM * N_HEADS];          // W . a_dst  [c][hd]
    __shared__ float    als[N_NODES * N_HEADS];       // alpha_src, all nodes
    __shared__ float    adn[N_HEADS];                 // alpha_dst, own node
    __shared__ unsigned msegu[N_HEADS];
    __shared__ float    dseg[N_HEADS];
    __shared__ float    M[N_NODES * N_HEADS];         // attention row [s][hd]
    __shared__ float    y[N_HEADS * CDIM];
    __shared__ float    sv[CDIM];
    __shared__ float4   red4[N_HEADS][64];            // out_gat partials
    __shared__ float    cred[8][32];                  // classifier partials

    // ---- issue ALL independent global loads up front ----------------------
    float4 xv[8];
#pragma unroll
    for (int k = 0; k < 8; ++k) xv[k] = ((const float4*)x)[t + k * 256];
    const float asr = a_src[t], adr = a_dst[t];
    const int es0 = edge_index[t],       ed0 = edge_index[E_BASE + t];
    const int es1 = edge_index[256 + t], ed1 = edge_index[E_BASE + 256 + t];
    float4 bias4 = make_float4(0.f, 0.f, 0.f, 0.f);
    if (t < 64) bias4 = ((const float4*)gat_bias)[t];
    float cb = 0.f;
    if (t < 32) cb = cls_b[t];

    // ---- LDS staging (drains only the loads above) ------------------------
#pragma unroll
    for (int k = 0; k < 8; ++k) {
        const int i = (t + k * 256) * 4, s = i >> 8, c = i & 255;
        xs[s * XS + c + 0] = xv[k].x;
        xs[s * XS + c + 1] = xv[k].y;
        xs[s * XS + c + 2] = xv[k].z;
        xs[s * XS + c + 3] = xv[k].w;
    }
    asl[t] = asr;
    adl[t] = adr;
    if (t < 128) M[t] = 0.f;
    if (t < 4) { msegu[t] = 0u; dseg[t] = 0.f; }
    __syncthreads();

    // ---- Wa: thread t owns W row t (1 KB), unroll 32 -> 2 latency batches -
    {
        float accs[4] = {0.f, 0.f, 0.f, 0.f};
        float accd[4] = {0.f, 0.f, 0.f, 0.f};
        const float4* wr  = (const float4*)(W + (size_t)t * CDIM);
        const float4* as4 = (const float4*)asl;
        const float4* ad4 = (const float4*)adl;
#pragma unroll 32
        for (int j = 0; j < 64; ++j) {                // j -> head j>>4
            const float4 w = wr[j], av = as4[j], dv = ad4[j];
            const int hd = j >> 4;
            accs[hd] += w.x * av.x + w.y * av.y + w.z * av.z + w.w * av.w;
            accd[hd] += w.x * dv.x + w.y * dv.y + w.z * dv.z + w.w * dv.w;
        }
#pragma unroll
        for (int hd = 0; hd < 4; ++hd) {
            was[t * 4 + hd] = accs[hd];
            wad[t * 4 + hd] = accd[hd];
        }
    }
    __syncthreads();

    // ---- alphas: als[s,hd] = xs[s,:].was[:,hd]; adn = xs[n,:].wad[:,hd] ----
    if (t < 132) {
        if (t < 128) {
            const int s = t >> 2, hd = t & 3;
            const float* xrow = &xs[s * XS];
            float acc = 0.f;
#pragma unroll 8
            for (int c = 0; c < CDIM; ++c) acc += xrow[c] * was[c * 4 + hd];
            als[t] = acc;
        } else {
            const int hd = t - 128;
            const float* xrow = &xs[n * XS];
            float acc = 0.f;
#pragma unroll 8
            for (int c = 0; c < CDIM; ++c) acc += xrow[c] * wad[c * 4 + hd];
            adn[hd] = acc;
        }
    }
    __syncthreads();

    // ---- pass A: segment max (edges in registers, monotone-uint atomicMax)
    {
        const bool sl = (t < 32) && (t == n);         // self loop (s0=t,d=t)
#pragma unroll
        for (int hd = 0; hd < 4; ++hd) {
            float best = -INFINITY;
            if (ed0 == n) {
                float v = als[es0 * 4 + hd] + adn[hd];
                best = fmaxf(best, (v >= 0.f) ? v : NEG_SLOPE * v);
            }
            if (ed1 == n) {
                float v = als[es1 * 4 + hd] + adn[hd];
                best = fmaxf(best, (v >= 0.f) ? v : NEG_SLOPE * v);
            }
            if (sl) {
                float v = als[n * 4 + hd] + adn[hd];
                best = fmaxf(best, (v >= 0.f) ? v : NEG_SLOPE * v);
            }
            if (best > -INFINITY) {
                const int iv = __float_as_int(best);
                const unsigned key = (iv < 0) ? ~(unsigned)iv
                                              : ((unsigned)iv | 0x80000000u);
                atomicMax(&msegu[hd], key);
            }
        }
    }
    __syncthreads();

    float mx[4];
#pragma unroll
    for (int hd = 0; hd < 4; ++hd) {
        const unsigned key = msegu[hd];
        const int im = (key & 0x80000000u) ? (int)(key & 0x7fffffffu) : (int)~key;
        mx[hd] = __int_as_float(im);
    }

    // ---- pass B: exp, denom, unnormalized attention row -------------------
    {
        const bool sl = (t < 32) && (t == n);
#pragma unroll
        for (int hd = 0; hd < 4; ++hd) {
            if (ed0 == n) {
                float v = als[es0 * 4 + hd] + adn[hd];
                v = (v >= 0.f) ? v : NEG_SLOPE * v;
                const float ex = expf(v - mx[hd]);
                atomicAdd(&dseg[hd], ex);
                atomicAdd(&M[es0 * 4 + hd], ex);
            }
            if (ed1 == n) {
                float v = als[es1 * 4 + hd] + adn[hd];
                v = (v >= 0.f) ? v : NEG_SLOPE * v;
                const float ex = expf(v - mx[hd]);
                atomicAdd(&dseg[hd], ex);
                atomicAdd(&M[es1 * 4 + hd], ex);
            }
            if (sl) {
                float v = als[n * 4 + hd] + adn[hd];
                v = (v >= 0.f) ? v : NEG_SLOPE * v;
                const float ex = expf(v - mx[hd]);
                atomicAdd(&dseg[hd], ex);
                atomicAdd(&M[n * 4 + hd], ex);
            }
        }
    }
    __syncthreads();
    if (t < 128) M[t] /= dseg[t & 3];
    __syncthreads();

    // ---- y[hd,c] = sum_s M[s,hd] * xs[s,c] --------------------------------
    {
        const int hd = wavg;
        float a0 = 0.f, a1 = 0.f, a2 = 0.f, a3 = 0.f;
#pragma unroll
        for (int s = 0; s < N_NODES; ++s) {
            const float m = M[s * 4 + hd];            // wave-uniform broadcast
            const float* xrow = &xs[s * XS + lane];
            a0 += m * xrow[0];   a1 += m * xrow[64];
            a2 += m * xrow[128]; a3 += m * xrow[192];
        }
        y[hd * CDIM + lane]       = a0;
        y[hd * CDIM + lane + 64]  = a1;
        y[hd * CDIM + lane + 128] = a2;
        y[hd * CDIM + lane + 192] = a3;
    }
    __syncthreads();

    // ---- out_gat: coalesced float4 W reads, 4-way c-split + LDS reduce ----
    // wave g sums c in [64g,64g+64); lane q owns output cols 4q..4q+3
    // (all in head q>>4). W[c][4q..] across lanes = contiguous 1 KB: coalesced.
    {
        const int hd = lane >> 4;
        const float* yrow = &y[hd * CDIM];
        float4 acc = make_float4(0.f, 0.f, 0.f, 0.f);
#pragma unroll 16
        for (int cc = 0; cc < 64; ++cc) {
            const int c = wavg * 64 + cc;
            const float4 w4 = ((const float4*)(W + (size_t)c * CDIM))[lane];
            const float yv = yrow[c];
            acc.x += yv * w4.x; acc.y += yv * w4.y;
            acc.z += yv * w4.z; acc.w += yv * w4.w;
        }
        red4[wavg][lane] = acc;
    }
    __syncthreads();
    if (t < 64) {
        const float4 s0 = red4[0][t], s1 = red4[1][t];
        const float4 s2 = red4[2][t], s3 = red4[3][t];
        float v0 = s0.x + s1.x + s2.x + s3.x + bias4.x;
        float v1 = s0.y + s1.y + s2.y + s3.y + bias4.y;
        float v2 = s0.z + s1.z + s2.z + s3.z + bias4.z;
        float v3 = s0.w + s1.w + s2.w + s3.w + bias4.w;
        sv[4 * t + 0] = v0 / (1.0f + expf(-v0));
        sv[4 * t + 1] = v1 / (1.0f + expf(-v1));
        sv[4 * t + 2] = v2 / (1.0f + expf(-v2));
        sv[4 * t + 3] = v3 / (1.0f + expf(-v3));
    }
    __syncthreads();

    // ---- classifier: 8 groups x 32 cols, fully unrolled (1 flight batch) --
    {
        const int j = t & 31, g8 = t >> 5;
        float a = 0.f;
#pragma unroll
        for (int c0 = 0; c0 < 32; ++c0) {
            const int c = g8 * 32 + c0;
            a += sv[c] * cls_W[c * 32 + j];           // coalesced
        }
        cred[g8][j] = a;
    }
    __syncthreads();
    if (t < 32) {
        float s2 = cb;
#pragma unroll
        for (int g2 = 0; g2 < 8; ++g2) s2 += cred[g2][t];
        out[n * 32 + t] = s2;
    }
}

// ---------------------------------------------------------------------------
extern "C" void kernel_launch(void* const* d_in, const int* in_sizes, int n_in,
                              void* d_out, int out_size, void* d_ws, size_t ws_size,
                              hipStream_t stream) {
    const float* roi   = (const float*)d_in[0];
    const int*   eidx  = (const int*)d_in[1];
    const float* W     = (const float*)d_in[2];
    const float* a_src = (const float*)d_in[3];
    const float* a_dst = (const float*)d_in[4];
    const float* gbias = (const float*)d_in[5];
    const float* clsW  = (const float*)d_in[6];
    const float* clsb  = (const float*)d_in[7];
    float* out = (float*)d_out;

    float* x = (float*)d_ws;                   // [8192] floats

    pool_kernel<<<(N_NODES * CDIM) / 4, 256, 0, stream>>>(roi, x);
    gat_kernel<<<N_NODES, 256, 0, stream>>>(eidx, x, W, a_src, a_dst,
                                            gbias, clsW, clsb, out);
}